// Round 1
// baseline (108.896 us; speedup 1.0000x reference)
//
#include <hip/hip_runtime.h>

#define NCLS 20
#define HW   (512 * 512)
#define TPB  256
#define PPT  2   // pixels per thread (float2 loads)

// Per-batch accumulator layout in d_ws (stride 64 uints):
//   [0] float lseg_sum   [1] float fcl_sum
//   [2..21]  cnt_tgt[c]  [22..41] cnt_pred[c]  [42..61] tp[c]
#define ACC_STRIDE 64

__global__ __launch_bounds__(TPB) void seg_main(
    const float* __restrict__ pred,
    const float* __restrict__ tgt,
    unsigned* __restrict__ acc)
{
    __shared__ unsigned h_tgt[NCLS], h_pred[NCLS], h_tp[NCLS];
    __shared__ float red[8];

    const int tid = threadIdx.x;
    if (tid < NCLS) { h_tgt[tid] = 0u; h_pred[tid] = 0u; h_tp[tid] = 0u; }
    __syncthreads();

    const int b = blockIdx.y;
    const size_t pix  = ((size_t)blockIdx.x * TPB + tid) * PPT;
    const size_t base = (size_t)b * NCLS * HW + pix;

    // ---- targets: recover label per pixel (one-hot -> argmax) ----
    int lab[PPT];
#pragma unroll
    for (int j = 0; j < PPT; ++j) lab[j] = 0;
#pragma unroll
    for (int c = 0; c < NCLS; ++c) {
        float2 tv = *reinterpret_cast<const float2*>(tgt + base + (size_t)c * HW);
        if (tv.x > 0.5f) lab[0] = c;
        if (tv.y > 0.5f) lab[1] = c;
    }

    // ---- predictions: load all channels, track max + argmax ----
    float x[NCLS][PPT];
    float m[PPT];
    int   pa[PPT];
#pragma unroll
    for (int j = 0; j < PPT; ++j) { m[j] = -1e30f; pa[j] = 0; }
#pragma unroll
    for (int c = 0; c < NCLS; ++c) {
        float2 v = *reinterpret_cast<const float2*>(pred + base + (size_t)c * HW);
        x[c][0] = v.x; x[c][1] = v.y;
#pragma unroll
        for (int j = 0; j < PPT; ++j)
            if (x[c][j] > m[j]) { m[j] = x[c][j]; pa[j] = c; }
    }

    // ---- softmax: e = exp(x - m), s = sum e ----
    float s[PPT];
#pragma unroll
    for (int j = 0; j < PPT; ++j) s[j] = 0.0f;
#pragma unroll
    for (int c = 0; c < NCLS; ++c) {
#pragma unroll
        for (int j = 0; j < PPT; ++j) {
            float e = __expf(x[c][j] - m[j]);
            x[c][j] = e;
            s[j] += e;
        }
    }

    // ---- BCE (lseg) per pixel, capture p_label for focal ----
    float lseg[PPT], plab[PPT];
#pragma unroll
    for (int j = 0; j < PPT; ++j) { lseg[j] = 0.0f; plab[j] = 0.0f; s[j] = 1.0f / s[j]; }
#pragma unroll
    for (int c = 0; c < NCLS; ++c) {
#pragma unroll
        for (int j = 0; j < PPT; ++j) {
            float p   = x[c][j] * s[j];
            bool  isl = (c == lab[j]);
            float q   = isl ? p : fmaxf(1.0f - p, 0.0f);
            lseg[j]  -= fmaxf(__logf(q), -100.0f);   // torch clamps log at -100
            plab[j]   = isl ? p : plab[j];
        }
    }

    float tl = 0.0f, tf = 0.0f;
#pragma unroll
    for (int j = 0; j < PPT; ++j) {
        tl += lseg[j];
        float om = 1.0f - plab[j];
        tf += -__logf(plab[j] + 1e-9f) * om * om;    // focal, gamma=2
    }

    // ---- block-local class histograms ----
#pragma unroll
    for (int j = 0; j < PPT; ++j) {
        atomicAdd(&h_tgt[lab[j]], 1u);
        atomicAdd(&h_pred[pa[j]], 1u);
        if (pa[j] == lab[j]) atomicAdd(&h_tp[lab[j]], 1u);
    }

    // ---- reduce the float sums: wave shuffle then cross-wave via LDS ----
#pragma unroll
    for (int off = 32; off > 0; off >>= 1) {
        tl += __shfl_down(tl, off, 64);
        tf += __shfl_down(tf, off, 64);
    }
    const int wid = tid >> 6, lane = tid & 63;
    if (lane == 0) { red[wid] = tl; red[4 + wid] = tf; }
    __syncthreads();   // also makes h_* histogram atomics visible

    unsigned* ab = acc + (size_t)b * ACC_STRIDE;
    if (tid == 0) {
        float a = red[0] + red[1] + red[2] + red[3];
        float f = red[4] + red[5] + red[6] + red[7];
        atomicAdd(reinterpret_cast<float*>(ab + 0), a);
        atomicAdd(reinterpret_cast<float*>(ab + 1), f);
    }
    if (tid < NCLS) {
        atomicAdd(&ab[2  + tid], h_tgt[tid]);
        atomicAdd(&ab[22 + tid], h_pred[tid]);
        atomicAdd(&ab[42 + tid], h_tp[tid]);
    }
}

__global__ void seg_final(const unsigned* __restrict__ acc, float* __restrict__ out, int nb)
{
    if (threadIdx.x == 0 && blockIdx.x == 0) {
        float total = 0.0f;
        for (int b = 0; b < nb; ++b) {
            const unsigned* ab = acc + (size_t)b * ACC_STRIDE;
            const float*    fs = reinterpret_cast<const float*>(ab);
            float lseg = fs[0] * (1.0f / ((float)NCLS * (float)HW));
            float fcl  = fs[1] * (1.0f / (float)HW);
            float ious = 0.0f;
            int   present = 0;
            for (int c = 0; c < NCLS; ++c) {
                unsigned tp = ab[42 + c], tg = ab[2 + c], pd = ab[22 + c];
                unsigned denom = tg + pd - tp;           // tp + fp + fn
                if (tg > 0) ++present;
                if (denom > 0) ious += (float)tp / (float)denom;
            }
            float iou = (present > 0) ? (ious / (float)present) : 0.0f;
            total += lseg + (1.0f - iou) + fcl;
        }
        out[0] = total / (float)nb;
    }
}

extern "C" void kernel_launch(void* const* d_in, const int* in_sizes, int n_in,
                              void* d_out, int out_size, void* d_ws, size_t ws_size,
                              hipStream_t stream)
{
    const float* pred = (const float*)d_in[0];
    const float* tgt  = (const float*)d_in[1];
    float* out = (float*)d_out;
    unsigned* acc = (unsigned*)d_ws;

    const int nb = in_sizes[0] / (NCLS * HW);   // batch = 8

    hipMemsetAsync(acc, 0, (size_t)nb * ACC_STRIDE * sizeof(unsigned), stream);

    dim3 grid(HW / (TPB * PPT), nb);            // (512, 8)
    seg_main<<<grid, TPB, 0, stream>>>(pred, tgt, acc);
    seg_final<<<1, 64, 0, stream>>>(acc, out, nb);
}